// Round 1
// baseline (103.964 us; speedup 1.0000x reference)
//
#include <hip/hip_runtime.h>

#define TBL 8192      // lookup table entries
#define NMAT 1024     // N
#define TILES 16      // 1024/64 tiles per dim
#define TPB 136       // tile-units per batch: 16 diag + 120 off-diag pairs

// ---------------------------------------------------------------------------
// Kernel 1: tabulate o(x) = sigmoid(w3 . relu(W2 . relu(x*w1+b1) + b2) + b3)
// at cell midpoints x = (e+0.5)/TBL. Exact fp32 MLP, 8192 threads.
// ---------------------------------------------------------------------------
__global__ void build_table_kernel(const float* __restrict__ w1,
                                   const float* __restrict__ b1,
                                   const float* __restrict__ w2,
                                   const float* __restrict__ b2,
                                   const float* __restrict__ w3,
                                   const float* __restrict__ b3,
                                   float* __restrict__ table) {
    int e = blockIdx.x * blockDim.x + threadIdx.x;
    if (e >= TBL) return;
    float x = (e + 0.5f) * (1.0f / TBL);
    float h1[32];
#pragma unroll
    for (int h = 0; h < 32; ++h)
        h1[h] = fmaxf(fmaf(x, w1[h], b1[h]), 0.0f);
    float f = b3[0];
#pragma unroll 4
    for (int k = 0; k < 32; ++k) {
        float acc = b2[k];
#pragma unroll
        for (int h = 0; h < 32; ++h)
            acc = fmaf(h1[h], w2[h * 32 + k], acc);
        f = fmaf(fmaxf(acc, 0.0f), w3[k], f);
    }
    table[e] = 1.0f / (1.0f + expf(-f));
}

// ---------------------------------------------------------------------------
// Kernel 2: per 64x64 tile pair, lookup + mask + symmetrize + zero-diag.
// All global traffic is coalesced float4; transpose via padded LDS tile.
// ---------------------------------------------------------------------------
__global__ __launch_bounds__(256)
void apply_kernel(const float* __restrict__ sim,
                  const int* __restrict__ nm,
                  const float* __restrict__ tableg,
                  float* __restrict__ out) {
    __shared__ float tbl[TBL];          // 32 KB
    __shared__ float buf[64][65];       // 16.6 KB, +1 pad -> <=2-way banks
    __shared__ float mI[64];
    __shared__ float mJ[64];

    const int t = threadIdx.x;

    // stage lookup table (float4, coalesced)
    {
        const float4* tg4 = (const float4*)tableg;
        float4* tb4 = (float4*)tbl;
#pragma unroll
        for (int i = 0; i < TBL / 4 / 256; ++i)
            tb4[t + i * 256] = tg4[t + i * 256];
    }

    const int b = blockIdx.x / TPB;
    const int u = blockIdx.x - b * TPB;
    int I, J;
    if (u < TILES) {
        I = u; J = u;
    } else {
        int p = u - TILES;
        I = 0;
        while (p >= (TILES - 1) - I) { p -= (TILES - 1) - I; ++I; }
        J = I + 1 + p;
    }

    if (t < 64)       mI[t]      = nm[b * NMAT + I * 64 + t]        ? 1.0f : 0.0f;
    else if (t < 128) mJ[t - 64] = nm[b * NMAT + J * 64 + (t - 64)] ? 1.0f : 0.0f;
    __syncthreads();

    const int q  = t & 15;   // float4 group: cols 4q..4q+3
    const int r0 = t >> 4;   // 0..15 ; rows r0 + 16k
    const int c0 = q << 2;
    const float4* sim4 = (const float4*)sim;
    float4* out4 = (float4*)out;
    const int bb = b * NMAT * NMAT;

    if (I != J) {
        // ---- Phase 1: o for tile (J,I) -> buf[r][c] ----
#pragma unroll
        for (int k = 0; k < 4; ++k) {
            int r = r0 + 16 * k;
            int base4 = (bb + (J * 64 + r) * NMAT + I * 64) >> 2;
            float4 x4 = sim4[base4 + q];
            float mr = mJ[r];
            int i0 = min((int)(x4.x * (float)TBL), TBL - 1);
            int i1 = min((int)(x4.y * (float)TBL), TBL - 1);
            int i2 = min((int)(x4.z * (float)TBL), TBL - 1);
            int i3 = min((int)(x4.w * (float)TBL), TBL - 1);
            buf[r][c0 + 0] = tbl[i0] * (mr * mI[c0 + 0]);
            buf[r][c0 + 1] = tbl[i1] * (mr * mI[c0 + 1]);
            buf[r][c0 + 2] = tbl[i2] * (mr * mI[c0 + 2]);
            buf[r][c0 + 3] = tbl[i3] * (mr * mI[c0 + 3]);
        }
        __syncthreads();

        // ---- Phase 2: tile (I,J): o1 + mirror from buf, write coalesced ----
        float res[16];
#pragma unroll
        for (int k = 0; k < 4; ++k) {
            int r = r0 + 16 * k;
            int base4 = (bb + (I * 64 + r) * NMAT + J * 64) >> 2;
            float4 x4 = sim4[base4 + q];
            float mr = mI[r];
            int i0 = min((int)(x4.x * (float)TBL), TBL - 1);
            int i1 = min((int)(x4.y * (float)TBL), TBL - 1);
            int i2 = min((int)(x4.z * (float)TBL), TBL - 1);
            int i3 = min((int)(x4.w * (float)TBL), TBL - 1);
            float o0 = tbl[i0] * (mr * mJ[c0 + 0]);
            float o1 = tbl[i1] * (mr * mJ[c0 + 1]);
            float o2 = tbl[i2] * (mr * mJ[c0 + 2]);
            float o3 = tbl[i3] * (mr * mJ[c0 + 3]);
            res[4 * k + 0] = 0.5f * (o0 + buf[c0 + 0][r]);
            res[4 * k + 1] = 0.5f * (o1 + buf[c0 + 1][r]);
            res[4 * k + 2] = 0.5f * (o2 + buf[c0 + 2][r]);
            res[4 * k + 3] = 0.5f * (o3 + buf[c0 + 3][r]);
            float4 v;
            v.x = res[4 * k + 0]; v.y = res[4 * k + 1];
            v.z = res[4 * k + 2]; v.w = res[4 * k + 3];
            out4[base4 + q] = v;
        }
        __syncthreads();

        // ---- Phase 3: stash res, then write mirrored tile (J,I) coalesced ----
#pragma unroll
        for (int k = 0; k < 4; ++k) {
            int r = r0 + 16 * k;
            buf[r][c0 + 0] = res[4 * k + 0];
            buf[r][c0 + 1] = res[4 * k + 1];
            buf[r][c0 + 2] = res[4 * k + 2];
            buf[r][c0 + 3] = res[4 * k + 3];
        }
        __syncthreads();
#pragma unroll
        for (int k = 0; k < 4; ++k) {
            int r = r0 + 16 * k;
            int base4 = (bb + (J * 64 + r) * NMAT + I * 64) >> 2;
            float4 v;
            v.x = buf[c0 + 0][r];
            v.y = buf[c0 + 1][r];
            v.z = buf[c0 + 2][r];
            v.w = buf[c0 + 3][r];
            out4[base4 + q] = v;
        }
    } else {
        // ---- Diagonal tile ----
#pragma unroll
        for (int k = 0; k < 4; ++k) {
            int r = r0 + 16 * k;
            int base4 = (bb + (I * 64 + r) * NMAT + I * 64) >> 2;
            float4 x4 = sim4[base4 + q];
            float mr = mI[r];
            int i0 = min((int)(x4.x * (float)TBL), TBL - 1);
            int i1 = min((int)(x4.y * (float)TBL), TBL - 1);
            int i2 = min((int)(x4.z * (float)TBL), TBL - 1);
            int i3 = min((int)(x4.w * (float)TBL), TBL - 1);
            buf[r][c0 + 0] = tbl[i0] * (mr * mI[c0 + 0]);
            buf[r][c0 + 1] = tbl[i1] * (mr * mI[c0 + 1]);
            buf[r][c0 + 2] = tbl[i2] * (mr * mI[c0 + 2]);
            buf[r][c0 + 3] = tbl[i3] * (mr * mI[c0 + 3]);
        }
        __syncthreads();
#pragma unroll
        for (int k = 0; k < 4; ++k) {
            int r = r0 + 16 * k;
            int base4 = (bb + (I * 64 + r) * NMAT + I * 64) >> 2;
            float4 v;
            v.x = (r == c0 + 0) ? 0.0f : 0.5f * (buf[r][c0 + 0] + buf[c0 + 0][r]);
            v.y = (r == c0 + 1) ? 0.0f : 0.5f * (buf[r][c0 + 1] + buf[c0 + 1][r]);
            v.z = (r == c0 + 2) ? 0.0f : 0.5f * (buf[r][c0 + 2] + buf[c0 + 2][r]);
            v.w = (r == c0 + 3) ? 0.0f : 0.5f * (buf[r][c0 + 3] + buf[c0 + 3][r]);
            out4[base4 + q] = v;
        }
    }
}

extern "C" void kernel_launch(void* const* d_in, const int* in_sizes, int n_in,
                              void* d_out, int out_size, void* d_ws, size_t ws_size,
                              hipStream_t stream) {
    const float* sim = (const float*)d_in[0];
    const int*   nm  = (const int*)d_in[1];
    const float* w1  = (const float*)d_in[2];
    const float* b1  = (const float*)d_in[3];
    const float* w2  = (const float*)d_in[4];
    const float* b2  = (const float*)d_in[5];
    const float* w3  = (const float*)d_in[6];
    const float* b3  = (const float*)d_in[7];
    float* out = (float*)d_out;
    float* table = (float*)d_ws;   // 32 KB scratch

    build_table_kernel<<<TBL / 256, 256, 0, stream>>>(w1, b1, w2, b2, w3, b3, table);
    apply_kernel<<<8 * TPB, 256, 0, stream>>>(sim, nm, table, out);
}

// Round 2
// 103.225 us; speedup vs baseline: 1.0072x; 1.0072x over previous
//
#include <hip/hip_runtime.h>
#include <hip/hip_fp16.h>

#define TBL 4096      // lookup table entries (fp16, 8 KB in LDS)
#define NMAT 1024     // N
#define TILES 16      // 1024/64 tiles per dim
#define TPB 136       // tile-units per batch: 16 diag + 120 off-diag pairs

// ---------------------------------------------------------------------------
// Kernel 1: tabulate o(x) = sigmoid(w3 . relu(W2 . relu(x*w1+b1) + b2) + b3)
// at cell midpoints x = (e+0.5)/TBL. Exact fp32 MLP, fp16 storage.
// ---------------------------------------------------------------------------
__global__ void build_table_kernel(const float* __restrict__ w1,
                                   const float* __restrict__ b1,
                                   const float* __restrict__ w2,
                                   const float* __restrict__ b2,
                                   const float* __restrict__ w3,
                                   const float* __restrict__ b3,
                                   __half* __restrict__ table) {
    int e = blockIdx.x * blockDim.x + threadIdx.x;
    if (e >= TBL) return;
    float x = (e + 0.5f) * (1.0f / TBL);
    float h1[32];
#pragma unroll
    for (int h = 0; h < 32; ++h)
        h1[h] = fmaxf(fmaf(x, w1[h], b1[h]), 0.0f);
    float f = b3[0];
#pragma unroll 4
    for (int k = 0; k < 32; ++k) {
        float acc = b2[k];
#pragma unroll
        for (int h = 0; h < 32; ++h)
            acc = fmaf(h1[h], w2[h * 32 + k], acc);
        f = fmaf(fmaxf(acc, 0.0f), w3[k], f);
    }
    table[e] = __float2half(1.0f / (1.0f + expf(-f)));
}

// ---------------------------------------------------------------------------
// Kernel 2: per 64x64 tile pair, lookup + mask + symmetrize + zero-diag.
// LDS = 8K table + 16.6K transpose buf + masks = 25.2 KB -> 6 blocks/CU
// -> all 1088 blocks co-resident (no dispatch waves, no tail).
// ---------------------------------------------------------------------------
__global__ __launch_bounds__(256)
void apply_kernel(const float* __restrict__ sim,
                  const int* __restrict__ nm,
                  const __half* __restrict__ tableg,
                  float* __restrict__ out) {
    __shared__ __half tbl[TBL];         // 8 KB
    __shared__ float buf[64][65];       // 16.6 KB, +1 pad
    __shared__ float mI[64];
    __shared__ float mJ[64];

    const int t = threadIdx.x;

    // stage lookup table (float4 = 8 halves per load, coalesced)
    {
        const float4* tg4 = (const float4*)tableg;
        float4* tb4 = (float4*)tbl;
#pragma unroll
        for (int i = 0; i < TBL / 8 / 256; ++i)
            tb4[t + i * 256] = tg4[t + i * 256];
    }

    const int b = blockIdx.x / TPB;
    const int u = blockIdx.x - b * TPB;
    int I, J;
    if (u < TILES) {
        I = u; J = u;
    } else {
        int p = u - TILES;
        I = 0;
        while (p >= (TILES - 1) - I) { p -= (TILES - 1) - I; ++I; }
        J = I + 1 + p;
    }

    if (t < 64)       mI[t]      = nm[b * NMAT + I * 64 + t]        ? 1.0f : 0.0f;
    else if (t < 128) mJ[t - 64] = nm[b * NMAT + J * 64 + (t - 64)] ? 1.0f : 0.0f;
    __syncthreads();

    const int q  = t & 15;   // float4 group: cols 4q..4q+3
    const int r0 = t >> 4;   // 0..15 ; rows r0 + 16k
    const int c0 = q << 2;
    const float4* sim4 = (const float4*)sim;
    float4* out4 = (float4*)out;
    const int bb = b * NMAT * NMAT;

    if (I != J) {
        // ---- Phase 1: o for tile (J,I) -> buf[r][c] ----
#pragma unroll
        for (int k = 0; k < 4; ++k) {
            int r = r0 + 16 * k;
            int base4 = (bb + (J * 64 + r) * NMAT + I * 64) >> 2;
            float4 x4 = sim4[base4 + q];
            float mr = mJ[r];
            int i0 = min((int)(x4.x * (float)TBL), TBL - 1);
            int i1 = min((int)(x4.y * (float)TBL), TBL - 1);
            int i2 = min((int)(x4.z * (float)TBL), TBL - 1);
            int i3 = min((int)(x4.w * (float)TBL), TBL - 1);
            buf[r][c0 + 0] = __half2float(tbl[i0]) * (mr * mI[c0 + 0]);
            buf[r][c0 + 1] = __half2float(tbl[i1]) * (mr * mI[c0 + 1]);
            buf[r][c0 + 2] = __half2float(tbl[i2]) * (mr * mI[c0 + 2]);
            buf[r][c0 + 3] = __half2float(tbl[i3]) * (mr * mI[c0 + 3]);
        }
        __syncthreads();

        // ---- Phase 2: tile (I,J): o + mirror from buf, write coalesced ----
        float res[16];
#pragma unroll
        for (int k = 0; k < 4; ++k) {
            int r = r0 + 16 * k;
            int base4 = (bb + (I * 64 + r) * NMAT + J * 64) >> 2;
            float4 x4 = sim4[base4 + q];
            float mr = mI[r];
            int i0 = min((int)(x4.x * (float)TBL), TBL - 1);
            int i1 = min((int)(x4.y * (float)TBL), TBL - 1);
            int i2 = min((int)(x4.z * (float)TBL), TBL - 1);
            int i3 = min((int)(x4.w * (float)TBL), TBL - 1);
            float o0 = __half2float(tbl[i0]) * (mr * mJ[c0 + 0]);
            float o1 = __half2float(tbl[i1]) * (mr * mJ[c0 + 1]);
            float o2 = __half2float(tbl[i2]) * (mr * mJ[c0 + 2]);
            float o3 = __half2float(tbl[i3]) * (mr * mJ[c0 + 3]);
            res[4 * k + 0] = 0.5f * (o0 + buf[c0 + 0][r]);
            res[4 * k + 1] = 0.5f * (o1 + buf[c0 + 1][r]);
            res[4 * k + 2] = 0.5f * (o2 + buf[c0 + 2][r]);
            res[4 * k + 3] = 0.5f * (o3 + buf[c0 + 3][r]);
            float4 v;
            v.x = res[4 * k + 0]; v.y = res[4 * k + 1];
            v.z = res[4 * k + 2]; v.w = res[4 * k + 3];
            out4[base4 + q] = v;
        }
        __syncthreads();

        // ---- Phase 3: stash res, then write mirrored tile (J,I) coalesced ----
#pragma unroll
        for (int k = 0; k < 4; ++k) {
            int r = r0 + 16 * k;
            buf[r][c0 + 0] = res[4 * k + 0];
            buf[r][c0 + 1] = res[4 * k + 1];
            buf[r][c0 + 2] = res[4 * k + 2];
            buf[r][c0 + 3] = res[4 * k + 3];
        }
        __syncthreads();
#pragma unroll
        for (int k = 0; k < 4; ++k) {
            int r = r0 + 16 * k;
            int base4 = (bb + (J * 64 + r) * NMAT + I * 64) >> 2;
            float4 v;
            v.x = buf[c0 + 0][r];
            v.y = buf[c0 + 1][r];
            v.z = buf[c0 + 2][r];
            v.w = buf[c0 + 3][r];
            out4[base4 + q] = v;
        }
    } else {
        // ---- Diagonal tile ----
#pragma unroll
        for (int k = 0; k < 4; ++k) {
            int r = r0 + 16 * k;
            int base4 = (bb + (I * 64 + r) * NMAT + I * 64) >> 2;
            float4 x4 = sim4[base4 + q];
            float mr = mI[r];
            int i0 = min((int)(x4.x * (float)TBL), TBL - 1);
            int i1 = min((int)(x4.y * (float)TBL), TBL - 1);
            int i2 = min((int)(x4.z * (float)TBL), TBL - 1);
            int i3 = min((int)(x4.w * (float)TBL), TBL - 1);
            buf[r][c0 + 0] = __half2float(tbl[i0]) * (mr * mI[c0 + 0]);
            buf[r][c0 + 1] = __half2float(tbl[i1]) * (mr * mI[c0 + 1]);
            buf[r][c0 + 2] = __half2float(tbl[i2]) * (mr * mI[c0 + 2]);
            buf[r][c0 + 3] = __half2float(tbl[i3]) * (mr * mI[c0 + 3]);
        }
        __syncthreads();
#pragma unroll
        for (int k = 0; k < 4; ++k) {
            int r = r0 + 16 * k;
            int base4 = (bb + (I * 64 + r) * NMAT + I * 64) >> 2;
            float4 v;
            v.x = (r == c0 + 0) ? 0.0f : 0.5f * (buf[r][c0 + 0] + buf[c0 + 0][r]);
            v.y = (r == c0 + 1) ? 0.0f : 0.5f * (buf[r][c0 + 1] + buf[c0 + 1][r]);
            v.z = (r == c0 + 2) ? 0.0f : 0.5f * (buf[r][c0 + 2] + buf[c0 + 2][r]);
            v.w = (r == c0 + 3) ? 0.0f : 0.5f * (buf[r][c0 + 3] + buf[c0 + 3][r]);
            out4[base4 + q] = v;
        }
    }
}

extern "C" void kernel_launch(void* const* d_in, const int* in_sizes, int n_in,
                              void* d_out, int out_size, void* d_ws, size_t ws_size,
                              hipStream_t stream) {
    const float* sim = (const float*)d_in[0];
    const int*   nm  = (const int*)d_in[1];
    const float* w1  = (const float*)d_in[2];
    const float* b1  = (const float*)d_in[3];
    const float* w2  = (const float*)d_in[4];
    const float* b2  = (const float*)d_in[5];
    const float* w3  = (const float*)d_in[6];
    const float* b3  = (const float*)d_in[7];
    float* out = (float*)d_out;
    __half* table = (__half*)d_ws;   // 8 KB scratch

    build_table_kernel<<<TBL / 256, 256, 0, stream>>>(w1, b1, w2, b2, w3, b3, table);
    apply_kernel<<<8 * TPB, 256, 0, stream>>>(sim, nm, table, out);
}